// Round 8
// baseline (80.775 us; speedup 1.0000x reference)
//
#include <hip/hip_runtime.h>
#include <hip/hip_bf16.h>

// GCN layer. N=50000, E=800000, D=128, D_OUT=128, f32 in/out.
// out = concat(mean_agg(feature,src,dst), feature) @ W.T + b
//
// R8: (1) GEMM BM=64 (782 blocks, 48KB LDS -> 3 blocks/CU, kills the 391-block tail)
//     (2) node_agg unroll 4 -> 16 gather chains in flight per wave

#define D_IN 128
#define NB 391          // buckets = ceil(50000/128)
#define BSHIFT 7
#define EPB 4096        // edges per coarse block
#define CAPMAX 2680     // NB*CAP < 2^20 (packed rstart)

typedef __attribute__((ext_vector_type(8))) short bf16x8;
typedef __attribute__((ext_vector_type(4))) float f32x4;

static __device__ inline unsigned short f2bf(float x) {
    union { float f; unsigned u; } c; c.f = x;
    unsigned u = c.u;
    unsigned r = u + 0x7FFFu + ((u >> 16) & 1u);
    return (unsigned short)(r >> 16);
}
static __device__ inline float bflo(unsigned u) { return __uint_as_float(u << 16); }
static __device__ inline float bfhi(unsigned u) { return __uint_as_float(u & 0xFFFF0000u); }

// ---- phase 0: f32->bf16: feature -> X[:,128:], W -> Wbf; + bcursor init ----
__global__ __launch_bounds__(256) void convert_kernel(const float* __restrict__ feat,
                                                      const float* __restrict__ W,
                                                      unsigned short* __restrict__ X,
                                                      unsigned short* __restrict__ Wbf,
                                                      int* __restrict__ bcursor,
                                                      int M, int blocks_f, int CAP) {
    int b = blockIdx.x;
    if (b < blocks_f) {
        size_t idx = ((size_t)b * 256 + threadIdx.x) * 8;
        if (idx >= (size_t)M * 128) return;
        int row = (int)(idx >> 7);
        int col = (int)(idx & 127);
        float4 v0 = *reinterpret_cast<const float4*>(feat + idx);
        float4 v1 = *reinterpret_cast<const float4*>(feat + idx + 4);
        uint4 p;
        p.x = (unsigned)f2bf(v0.x) | ((unsigned)f2bf(v0.y) << 16);
        p.y = (unsigned)f2bf(v0.z) | ((unsigned)f2bf(v0.w) << 16);
        p.z = (unsigned)f2bf(v1.x) | ((unsigned)f2bf(v1.y) << 16);
        p.w = (unsigned)f2bf(v1.z) | ((unsigned)f2bf(v1.w) << 16);
        *reinterpret_cast<uint4*>(X + (size_t)row * 256 + 128 + col) = p;
    } else if (b < blocks_f + 16) {
        int idx = ((b - blocks_f) * 256 + (int)threadIdx.x) * 8;
        if (idx >= 128 * 256) return;
        float4 v0 = *reinterpret_cast<const float4*>(W + idx);
        float4 v1 = *reinterpret_cast<const float4*>(W + idx + 4);
        uint4 p;
        p.x = (unsigned)f2bf(v0.x) | ((unsigned)f2bf(v0.y) << 16);
        p.y = (unsigned)f2bf(v0.z) | ((unsigned)f2bf(v0.w) << 16);
        p.z = (unsigned)f2bf(v1.x) | ((unsigned)f2bf(v1.y) << 16);
        p.w = (unsigned)f2bf(v1.z) | ((unsigned)f2bf(v1.w) << 16);
        *reinterpret_cast<uint4*>(Wbf + idx) = p;
    } else {
        for (int i = threadIdx.x; i < NB; i += 256) bcursor[i] = i * CAP;
    }
}

// ---- phase 1: coarse bucket scatter (LDS counting sort by dst>>7) ----
__global__ __launch_bounds__(256) void coarse_scatter_kernel(
    const int* __restrict__ src, const int* __restrict__ dst,
    int* __restrict__ bcursor, unsigned* __restrict__ bedges,
    int CAP, int nE) {
    __shared__ int hist[NB];
    __shared__ int lofs[NB + 1];
    __shared__ int rnk[NB];
    __shared__ int gbase[NB];
    __shared__ int wsum[4];
    __shared__ unsigned staged[EPB];

    const int tid = threadIdx.x;
    const int e0 = blockIdx.x * EPB;
    for (int i = tid; i < NB; i += 256) { hist[i] = 0; rnk[i] = 0; }
    __syncthreads();

    for (int k = 0; k < EPB; k += 256) {
        int e = e0 + k + tid;
        if (e < nE) atomicAdd(&hist[dst[e] >> BSHIFT], 1);
    }
    __syncthreads();

    {
        int a = (2 * tid < NB) ? hist[2 * tid] : 0;
        int c = (2 * tid + 1 < NB) ? hist[2 * tid + 1] : 0;
        int ps = a + c;
        int x = ps;
        int lane = tid & 63, wv = tid >> 6;
#pragma unroll
        for (int off = 1; off < 64; off <<= 1) {
            int y = __shfl_up(x, off);
            if (lane >= off) x += y;
        }
        if (lane == 63) wsum[wv] = x;
        __syncthreads();
        if (tid == 0) {
            int s = 0;
#pragma unroll
            for (int w = 0; w < 4; w++) { int v = wsum[w]; wsum[w] = s; s += v; }
        }
        __syncthreads();
        int excl = x - ps + wsum[wv];
        if (2 * tid < NB + 1) lofs[2 * tid] = excl;
        if (2 * tid + 1 < NB + 1) lofs[2 * tid + 1] = excl + a;
    }
    __syncthreads();

    for (int i = tid; i < NB; i += 256)
        if (hist[i] > 0) gbase[i] = atomicAdd(&bcursor[i], hist[i]);

    for (int k = 0; k < EPB; k += 256) {
        int e = e0 + k + tid;
        if (e < nE) {
            int d = dst[e];
            int bk = d >> BSHIFT;
            unsigned ed = ((unsigned)d << 16) | (unsigned)src[e];
            int r = atomicAdd(&rnk[bk], 1);
            staged[lofs[bk] + r] = ed;
        }
    }
    __syncthreads();

    int total = lofs[NB];
    for (int i = tid; i < total; i += 256) {
        unsigned ed = staged[i];
        int bk = (int)(ed >> 23);
        int addr = gbase[bk] + (i - lofs[bk]);
        if (addr < (bk + 1) * CAP) bedges[addr] = ed;
    }
}

// ---- phase 2: per-bucket fine counting sort by dst&127; emit packed rstart ----
__global__ __launch_bounds__(256) void fine_sort_kernel(
    unsigned* __restrict__ bedges, const int* __restrict__ bcursor,
    unsigned* __restrict__ rstart, int CAP, int N) {
    __shared__ int h[128];
    __shared__ int lofs[129];
    __shared__ int rnk[128];
    __shared__ unsigned staged[CAPMAX + 8];

    const int b = blockIdx.x;
    const int S = b * CAP;
    const int tid = threadIdx.x;
    int cnt = min(bcursor[b] - S, CAP);

    if (tid < 128) { h[tid] = 0; rnk[tid] = 0; }
    __syncthreads();
    for (int i = tid; i < cnt; i += 256) {
        unsigned ed = bedges[S + i];
        atomicAdd(&h[(ed >> 16) & 127], 1);
    }
    __syncthreads();
    if (tid < 64) {
        int a = h[2 * tid], c = h[2 * tid + 1];
        int ps = a + c;
        int x = ps;
#pragma unroll
        for (int off = 1; off < 64; off <<= 1) {
            int y = __shfl_up(x, off);
            if (tid >= off) x += y;
        }
        int excl = x - ps;
        lofs[2 * tid] = excl;
        lofs[2 * tid + 1] = excl + a;
        if (tid == 63) lofs[128] = x;
    }
    __syncthreads();
    for (int i = tid; i < cnt; i += 256) {
        unsigned ed = bedges[S + i];
        int ld = (ed >> 16) & 127;
        int r = atomicAdd(&rnk[ld], 1);
        staged[lofs[ld] + r] = ed;
    }
    __syncthreads();
    for (int i = tid; i < cnt; i += 256) bedges[S + i] = staged[i];
    if (tid < 128) {
        int node = b * 128 + tid;
        if (node < N)
            rstart[node] = (((unsigned)(S + lofs[tid])) << 12) | (unsigned)h[tid];
    }
}

// ---- phase 3: per-node mean over bf16 rows; quarter-wave, unroll 4 ----
__global__ __launch_bounds__(256) void node_agg_kernel(unsigned short* __restrict__ X,
                                                       const unsigned* __restrict__ bedges,
                                                       const unsigned* __restrict__ rstart, int N) {
    int wid = (int)((blockIdx.x * (size_t)blockDim.x + threadIdx.x) >> 6);
    if (wid >= N) return;
    const int lane = threadIdx.x & 63;
    const int q = lane >> 4;
    const int sl = lane & 15;
    const unsigned pk = rstart[wid];
    const int s = (int)(pk >> 12);
    const int cnt = (int)(pk & 4095u);
    const int e = s + cnt;
    const char* Xb = (const char*)X;
    const size_t coff = 256 + (size_t)sl * 16;

    float a0=0.f,a1=0.f,a2=0.f,a3=0.f,a4=0.f,a5=0.f,a6=0.f,a7=0.f;
    int j = s + q;
    // unroll 4: 4 edges per quarter in flight -> 16 chains per wave
    for (; j + 12 < e; j += 16) {
        int u0 = (int)(bedges[j] & 0xFFFFu);
        int u1 = (int)(bedges[j + 4] & 0xFFFFu);
        int u2 = (int)(bedges[j + 8] & 0xFFFFu);
        int u3 = (int)(bedges[j + 12] & 0xFFFFu);
        uint4 va = *reinterpret_cast<const uint4*>(Xb + (size_t)u0 * 512 + coff);
        uint4 vb = *reinterpret_cast<const uint4*>(Xb + (size_t)u1 * 512 + coff);
        uint4 vc = *reinterpret_cast<const uint4*>(Xb + (size_t)u2 * 512 + coff);
        uint4 vd = *reinterpret_cast<const uint4*>(Xb + (size_t)u3 * 512 + coff);
        a0 += (bflo(va.x) + bflo(vb.x)) + (bflo(vc.x) + bflo(vd.x));
        a1 += (bfhi(va.x) + bfhi(vb.x)) + (bfhi(vc.x) + bfhi(vd.x));
        a2 += (bflo(va.y) + bflo(vb.y)) + (bflo(vc.y) + bflo(vd.y));
        a3 += (bfhi(va.y) + bfhi(vb.y)) + (bfhi(vc.y) + bfhi(vd.y));
        a4 += (bflo(va.z) + bflo(vb.z)) + (bflo(vc.z) + bflo(vd.z));
        a5 += (bfhi(va.z) + bfhi(vb.z)) + (bfhi(vc.z) + bfhi(vd.z));
        a6 += (bflo(va.w) + bflo(vb.w)) + (bflo(vc.w) + bflo(vd.w));
        a7 += (bfhi(va.w) + bfhi(vb.w)) + (bfhi(vc.w) + bfhi(vd.w));
    }
    for (; j < e; j += 4) {
        int u = (int)(bedges[j] & 0xFFFFu);
        uint4 va = *reinterpret_cast<const uint4*>(Xb + (size_t)u * 512 + coff);
        a0 += bflo(va.x); a1 += bfhi(va.x);
        a2 += bflo(va.y); a3 += bfhi(va.y);
        a4 += bflo(va.z); a5 += bfhi(va.z);
        a6 += bflo(va.w); a7 += bfhi(va.w);
    }
    a0 += __shfl_down(a0, 32); a1 += __shfl_down(a1, 32);
    a2 += __shfl_down(a2, 32); a3 += __shfl_down(a3, 32);
    a4 += __shfl_down(a4, 32); a5 += __shfl_down(a5, 32);
    a6 += __shfl_down(a6, 32); a7 += __shfl_down(a7, 32);
    a0 += __shfl_down(a0, 16); a1 += __shfl_down(a1, 16);
    a2 += __shfl_down(a2, 16); a3 += __shfl_down(a3, 16);
    a4 += __shfl_down(a4, 16); a5 += __shfl_down(a5, 16);
    a6 += __shfl_down(a6, 16); a7 += __shfl_down(a7, 16);
    if (lane < 16) {
        float r = 1.0f / fmaxf((float)cnt, 1.0f);
        uint4 p;
        p.x = (unsigned)f2bf(a0 * r) | ((unsigned)f2bf(a1 * r) << 16);
        p.y = (unsigned)f2bf(a2 * r) | ((unsigned)f2bf(a3 * r) << 16);
        p.z = (unsigned)f2bf(a4 * r) | ((unsigned)f2bf(a5 * r) << 16);
        p.w = (unsigned)f2bf(a6 * r) | ((unsigned)f2bf(a7 * r) << 16);
        *reinterpret_cast<uint4*>((char*)X + (size_t)wid * 512 + sl * 16) = p;
    }
}

// ---- phase 4: out[M,128] = X[M,256]bf16 @ Wbf[128,256]^T + b via MFMA ----
// BM=64, BN=128: 782 blocks, LDS 48KB -> 3 blocks/CU.
__global__ __launch_bounds__(256) void gcn_gemm_kernel(
    const unsigned short* __restrict__ X, const unsigned short* __restrict__ Wbf,
    const float* __restrict__ bias, float* __restrict__ out, int M) {

    __shared__ unsigned short A_sh[64 * 128];   // [row][k] bf16, XOR-swizzled
    __shared__ unsigned short B_sh[128 * 128];
    char* Ab = (char*)A_sh;
    char* Bb = (char*)B_sh;
    const char* Xb = (const char*)X;
    const char* Wb = (const char*)Wbf;

    const int tid = threadIdx.x;
    const int n0 = blockIdx.x * 64;
    const int wid = tid >> 6;
    const int lane = tid & 63;
    const int wr = wid >> 1;          // 0,1: 32-row strip
    const int wc = wid & 1;           // 0,1: 64-col strip
    const int fr = lane & 15;
    const int fq = lane >> 4;

    f32x4 acc[2][4];
#pragma unroll
    for (int m = 0; m < 2; m++)
#pragma unroll
        for (int n = 0; n < 4; n++) acc[m][n] = (f32x4)(0.0f);

#pragma unroll
    for (int p = 0; p < 2; p++) {
        // stage A: 64 rows x 16 chunks = 1024 -> 4 iters
#pragma unroll
        for (int it = 0; it < 4; it++) {
            int idx = it * 256 + tid;
            int row = idx >> 4;           // 0..63
            int ch = idx & 15;
            int off = ((row << 8) + (ch << 4)) ^ ((row & 7) << 4);
            int nrow = n0 + row;
            uint4 va = make_uint4(0u, 0u, 0u, 0u);
            if (nrow < M)
                va = *reinterpret_cast<const uint4*>(Xb + (size_t)nrow * 512 + p * 256 + ch * 16);
            *reinterpret_cast<uint4*>(Ab + off) = va;
        }
        // stage B: 128 rows x 16 chunks = 2048 -> 8 iters
#pragma unroll
        for (int it = 0; it < 8; it++) {
            int idx = it * 256 + tid;
            int row = idx >> 4;           // 0..127
            int ch = idx & 15;
            int off = ((row << 8) + (ch << 4)) ^ ((row & 7) << 4);
            uint4 vb = *reinterpret_cast<const uint4*>(Wb + (size_t)row * 512 + p * 256 + ch * 16);
            *reinterpret_cast<uint4*>(Bb + off) = vb;
        }
        __syncthreads();

#pragma unroll
        for (int ks = 0; ks < 4; ks++) {
            const int k = ks * 32 + fq * 8;
            bf16x8 af[2], bf_[4];
#pragma unroll
            for (int m = 0; m < 2; m++) {
                int row = wr * 32 + m * 16 + fr;
                int off = ((row << 8) + (k << 1)) ^ ((row & 7) << 4);
                af[m] = *reinterpret_cast<const bf16x8*>(Ab + off);
            }
#pragma unroll
            for (int n = 0; n < 4; n++) {
                int col = wc * 64 + n * 16 + fr;
                int off = ((col << 8) + (k << 1)) ^ ((col & 7) << 4);
                bf_[n] = *reinterpret_cast<const bf16x8*>(Bb + off);
            }
#pragma unroll
            for (int m = 0; m < 2; m++)
#pragma unroll
                for (int n = 0; n < 4; n++)
                    acc[m][n] = __builtin_amdgcn_mfma_f32_16x16x32_bf16(af[m], bf_[n], acc[m][n], 0, 0, 0);
        }
        if (p == 0) __syncthreads();
    }

    float bv[4];
#pragma unroll
    for (int n = 0; n < 4; n++) bv[n] = bias[wc * 64 + n * 16 + fr];

#pragma unroll
    for (int m = 0; m < 2; m++) {
        int rbase = n0 + wr * 32 + m * 16 + fq * 4;
#pragma unroll
        for (int n = 0; n < 4; n++) {
            int col = wc * 64 + n * 16 + fr;
#pragma unroll
            for (int j = 0; j < 4; j++) {
                int r = rbase + j;
                if (r < M) out[(size_t)r * 128 + col] = acc[m][n][j] + bv[n];
            }
        }
    }
}

extern "C" void kernel_launch(void* const* d_in, const int* in_sizes, int n_in,
                              void* d_out, int out_size, void* d_ws, size_t ws_size,
                              hipStream_t stream) {
    const float* feature = (const float*)d_in[0];
    const int*   src     = (const int*)d_in[1];
    const int*   dst     = (const int*)d_in[2];
    const float* W       = (const float*)d_in[3];
    const float* bias    = (const float*)d_in[4];
    float* out = (float*)d_out;

    const int M  = in_sizes[0] / D_IN;   // 50000
    const int nE = in_sizes[1];          // 800000

    char* w = (char*)d_ws;
    unsigned short* X   = (unsigned short*)w;              // M*256 bf16
    unsigned short* Wbf = X + (size_t)M * 256;             // 128*256 bf16
    int* bcursor = (int*)(Wbf + 128 * 256);                // NB
    unsigned* rstart = (unsigned*)(bcursor + NB);          // M
    unsigned* bedges = (unsigned*)(rstart + M);            // NB*CAP

    size_t fixed = (size_t)((char*)bedges - w);
    long avail = (long)ws_size - (long)fixed;
    int CAP = (int)(avail / (NB * 4));
    if (CAP > CAPMAX) CAP = CAPMAX;
    if (CAP < 1) CAP = 1;

    const int blocks_f = (M * D_IN) / (256 * 8);           // 3125
    convert_kernel<<<blocks_f + 17, 256, 0, stream>>>(feature, W, X, Wbf, bcursor, M, blocks_f, CAP);
    {
        int blocks = (nE + EPB - 1) / EPB;                 // 196
        coarse_scatter_kernel<<<blocks, 256, 0, stream>>>(src, dst, bcursor, bedges, CAP, nE);
    }
    {
        int blocks = (M + 127) / 128;                      // 391
        fine_sort_kernel<<<blocks, 256, 0, stream>>>(bedges, bcursor, rstart, CAP, M);
    }
    {
        size_t totalT = (size_t)M * 64;
        int blocks = (int)((totalT + 255) / 256);
        node_agg_kernel<<<blocks, 256, 0, stream>>>(X, bedges, rstart, M);
    }
    {
        int blocks = (M + 63) / 64;                        // 782
        gcn_gemm_kernel<<<blocks, 256, 0, stream>>>(X, Wbf, bias, out, M);
    }
}